// Round 5
// baseline (386.296 us; speedup 1.0000x reference)
//
#include <hip/hip_runtime.h>

// RecursiveNN: 11-level binary tree, shared linear map W(128x256)+b, bf16 MFMA.
// pack_w: W -> per-lane MFMA B-fragment order (bf16), indexed by (N-tile, kk).
// tree128: one block = 128 contiguous leaves; fp32 gather + packed cvt -> LDS;
//   XOR-swizzled LDS (STRIDE=128, chunk^=row&15) -> 40 KiB -> 3 blocks/CU.
//   2x2 wave split: mw = M-half, nw = 64-col N-half; each wave holds 32 W
//   fragments (128 VGPR). Halves LDS A-read redundancy vs 4-way N-split.
// tree32: one block = one batch; final 5 levels (32->1); fp32 output.

typedef __bf16 bf16x8 __attribute__((ext_vector_type(8)));
typedef __bf16 bf16x4 __attribute__((ext_vector_type(4)));
typedef float f32x4 __attribute__((ext_vector_type(4)));

// Swizzled LDS offset: row stride 128 elems (256 B); 16B chunk index XORed
// with (row & 15) -> conflict-free for all access patterns used here, and
// all row-base offsets fold into ds instruction immediates.
__device__ __forceinline__ int sw_off(int row, int col) {
    return row * 128 + ((((col >> 3) ^ (row & 15)) << 3) | (col & 7));
}

// Pack W (fp32 128x256) into MFMA B-fragment lane order (bf16):
//   global frag gf = nt*8 + kk (N-tile nt = cols nt*16..+16), lane l:
//   elem j = W[o][d+j], o = nt*16 + (l&15), d = kk*32 + (l>>4)*8.
__global__ void pack_w_kernel(const float* __restrict__ W,
                              __bf16* __restrict__ wpack) {
    const int gf = blockIdx.x;       // 0..63
    const int l = threadIdx.x;       // 0..63
    const int nt = gf >> 3, kk = gf & 7;
    const int o = nt * 16 + (l & 15);
    const int d = kk * 32 + ((l >> 4) << 3);
    const float* src = W + o * 256 + d;
    bf16x8 h;
#pragma unroll
    for (int j = 0; j < 8; ++j) h[j] = (__bf16)src[j];
    *(bf16x8*)(wpack + (size_t)(gf * 64 + l) * 8) = h;
}

// One 16-output M-tile: reads 2*NOUT rows (pairs 2m,2m+1) from src (swizzled),
// computes 64 cols (nw half: 4 N-tiles), writes NOUT rows to dst (swizzled).
// Padded lanes clamp to row 0 (LDS broadcast, free).
template <int NOUT>
__device__ __forceinline__ void step_tile(
    const __bf16* __restrict__ src, __bf16* __restrict__ dst,
    const bf16x8* wf, const float* bval, int nw, int q, int lm)
{
    const int me = (NOUT >= 16) ? lm : (lm < NOUT ? lm : 0);
    f32x4 acc[4];
#pragma unroll
    for (int nl = 0; nl < 4; ++nl)
        acc[nl] = (f32x4){ bval[nl], bval[nl], bval[nl], bval[nl] };
#pragma unroll
    for (int kk = 0; kk < 8; ++kk) {
        const int row = 2 * me + (kk >> 2);            // k>=128 half selects +1
        const int col = (kk & 3) * 32 + q * 8;
        const bf16x8 af = *(const bf16x8*)&src[sw_off(row, col)];
#pragma unroll
        for (int nl = 0; nl < 4; ++nl)
            acc[nl] = __builtin_amdgcn_mfma_f32_16x16x32_bf16(
                af, wf[nl * 8 + kk], acc[nl], 0, 0, 0);
    }
#pragma unroll
    for (int nl = 0; nl < 4; ++nl) {
        const int col = (nw * 4 + nl) * 16 + lm;       // D col = lane&15
        const bf16x4 hv = __builtin_convertvector(acc[nl], bf16x4);
#pragma unroll
        for (int r = 0; r < 4; ++r) {
            const int row = q * 4 + r;                 // D row = quad*4+reg
            if (NOUT >= 16 || row < NOUT)
                dst[sw_off(row, col)] = hv[r];
        }
    }
}

// Final step: 4 src rows -> 2 roots straight to global (bf16).
__device__ __forceinline__ void final_tile(
    const __bf16* __restrict__ src, __bf16* __restrict__ yrow,
    const bf16x8* wf, const float* bval, int nw, int q, int lm)
{
    const int me = (lm < 2) ? lm : 0;
    f32x4 acc[4];
#pragma unroll
    for (int nl = 0; nl < 4; ++nl)
        acc[nl] = (f32x4){ bval[nl], bval[nl], bval[nl], bval[nl] };
#pragma unroll
    for (int kk = 0; kk < 8; ++kk) {
        const int row = 2 * me + (kk >> 2);
        const int col = (kk & 3) * 32 + q * 8;
        const bf16x8 af = *(const bf16x8*)&src[sw_off(row, col)];
#pragma unroll
        for (int nl = 0; nl < 4; ++nl)
            acc[nl] = __builtin_amdgcn_mfma_f32_16x16x32_bf16(
                af, wf[nl * 8 + kk], acc[nl], 0, 0, 0);
    }
#pragma unroll
    for (int nl = 0; nl < 4; ++nl) {
        const int col = (nw * 4 + nl) * 16 + lm;
        if (q == 0) {                                  // rows 0,1 = q0 regs 0,1
            yrow[0 * 128 + col] = (__bf16)acc[nl][0];
            yrow[1 * 128 + col] = (__bf16)acc[nl][1];
        }
    }
}

// Kernel 1: one block = 128 contiguous leaves of one batch. Schedule
// (dead-row recycling; all bases 16-row aligned for swizzle consistency):
//   s1: A[0:63]  -> S[0:31]     s2: A[64:127] -> A[0:31]
//   L2: S[0:31]+A[0:31] -> A[32:63]   L3: A[32:63] -> S[0:15]
//   L4: S[0:15] -> A[0:7]       L5: A[0:7] -> S[0:3]   L6: S[0:3] -> global
__global__ __launch_bounds__(256, 3) void tree128_kernel(
    const int* __restrict__ wid, const float* __restrict__ emb,
    const __bf16* __restrict__ wpack, const float* __restrict__ bias,
    __bf16* __restrict__ yout)
{
    __shared__ __align__(16) __bf16 A[128 * 128];  // 32 KiB
    __shared__ __align__(16) __bf16 S[32 * 128];   // 8 KiB -> 40 KiB total
    const int tid = threadIdx.x;
    const int batch = blockIdx.x >> 4;   // 16 groups of 128 leaves per batch
    const int grp = blockIdx.x & 15;
    const int wv = tid >> 6, nw = wv & 1, mw = wv >> 1;
    const int ln = tid & 63, q = ln >> 4, lm = ln & 15;

    // Gather 128 rows x 128 fp32 -> bf16 swizzled LDS (512B coalesced runs).
    {
        const int* wb = wid + batch * 2048 + grp * 128;
        int idreg[16];
#pragma unroll
        for (int i = 0; i < 16; ++i) idreg[i] = wb[(tid >> 5) + 8 * i];
#pragma unroll
        for (int i = 0; i < 16; ++i) {
            const int row = (tid >> 5) + 8 * i;
            const int c4 = tid & 31;
            const f32x4 v =
                *(const f32x4*)(emb + (size_t)idreg[i] * 128 + c4 * 4);
            *(bf16x4*)&A[sw_off(row, c4 * 4)] =
                __builtin_convertvector(v, bf16x4);
        }
    }

    // W fragments for this wave's 64 cols: 32 x bf16x8 = 128 VGPRs.
    bf16x8 wf[32];
    const bf16x8* wp = (const bf16x8*)wpack;
#pragma unroll
    for (int f = 0; f < 32; ++f) wf[f] = wp[(nw * 32 + f) * 64 + ln];
    float bval[4];
#pragma unroll
    for (int nl = 0; nl < 4; ++nl) bval[nl] = bias[(nw * 4 + nl) * 16 + lm];

    __syncthreads();

    step_tile<16>(A + (mw ? 32 * 128 : 0), S + (mw ? 16 * 128 : 0),
                  wf, bval, nw, q, lm);
    __syncthreads();
    step_tile<16>(A + (mw ? 96 * 128 : 64 * 128), A + (mw ? 16 * 128 : 0),
                  wf, bval, nw, q, lm);
    __syncthreads();
    step_tile<16>(mw ? A : S, A + (mw ? 48 * 128 : 32 * 128),
                  wf, bval, nw, q, lm);
    __syncthreads();
    if (mw == 0) step_tile<16>(A + 32 * 128, S, wf, bval, nw, q, lm);
    __syncthreads();
    if (mw == 0) step_tile<8>(S, A, wf, bval, nw, q, lm);
    __syncthreads();
    if (mw == 0) step_tile<4>(A, S, wf, bval, nw, q, lm);
    __syncthreads();
    if (mw == 0)
        final_tile(S, yout + (size_t)(batch * 32 + grp * 2) * 128,
                   wf, bval, nw, q, lm);
}

// Kernel 2: one block = one batch; 32 subtree roots -> 5 levels -> fp32 row.
// (4-way N-split, padded-stride LDS; small enough that it doesn't matter.)
#define STRIDE 136
__global__ __launch_bounds__(256) void tree32_kernel(
    const __bf16* __restrict__ yin, const __bf16* __restrict__ wpack,
    const float* __restrict__ bias, float* __restrict__ out)
{
    __shared__ __align__(16) __bf16 buf[2][32 * STRIDE];  // ~17.4 KB
    const int tid = threadIdx.x;
    const int batch = blockIdx.x;
    const int wv = tid >> 6, ln = tid & 63, q = ln >> 4, lm = ln & 15;

    // wave wv owns N-tiles {2wv, 2wv+1}: frag f=nl*8+kk at gf = 16wv + f.
    bf16x8 wf[16];
    const bf16x8* wp = (const bf16x8*)wpack;
#pragma unroll
    for (int f = 0; f < 16; ++f) wf[f] = wp[(16 * wv + f) * 64 + ln];
    float bval[2];
    bval[0] = bias[(2 * wv + 0) * 16 + lm];
    bval[1] = bias[(2 * wv + 1) * 16 + lm];

#pragma unroll
    for (int i = 0; i < 2; ++i) {
        const int flat = tid + 256 * i;
        const int row = flat >> 4;
        const int c8 = flat & 15;
        const bf16x8 v =
            *(const bf16x8*)(yin + (size_t)(batch * 32 + row) * 128 + c8 * 8);
        *(bf16x8*)&buf[0][row * STRIDE + c8 * 8] = v;
    }
    __syncthreads();

    int nin = 32, rb = 0;
    while (nin > 1) {
        const int nout = nin >> 1;
        const int me = (lm < nout) ? lm : 0;
        bf16x8 af[8];
#pragma unroll
        for (int kk = 0; kk < 8; ++kk) {
            const int hi = kk >> 2;
            const int col = (kk & 3) * 32 + q * 8;
            af[kk] = *(const bf16x8*)&buf[rb][(2 * me + hi) * STRIDE + col];
        }
#pragma unroll
        for (int nl = 0; nl < 2; ++nl) {
            f32x4 acc = { bval[nl], bval[nl], bval[nl], bval[nl] };
#pragma unroll
            for (int kk = 0; kk < 8; ++kk)
                acc = __builtin_amdgcn_mfma_f32_16x16x32_bf16(
                    af[kk], wf[nl * 8 + kk], acc, 0, 0, 0);
            const int col = (2 * wv + nl) * 16 + lm;
            if (nout == 1) {
                if (q == 0) out[(size_t)batch * 128 + col] = acc[0];
            } else {
                const bf16x4 hv = __builtin_convertvector(acc, bf16x4);
#pragma unroll
                for (int r = 0; r < 4; ++r) {
                    const int row = q * 4 + r;
                    if (row < nout)
                        buf[rb ^ 1][row * STRIDE + col] = hv[r];
                }
            }
        }
        __syncthreads();
        rb ^= 1;
        nin = nout;
    }
}

extern "C" void kernel_launch(void* const* d_in, const int* in_sizes, int n_in,
                              void* d_out, int out_size, void* d_ws, size_t ws_size,
                              hipStream_t stream) {
    const int*   wid = (const int*)d_in[0];      // (256, 2048) int32
    const float* emb = (const float*)d_in[1];    // (100000, 128) fp32
    const float* W   = (const float*)d_in[2];    // (128, 256) fp32
    const float* b   = (const float*)d_in[3];    // (128,) fp32
    float* out = (float*)d_out;                  // (256, 128) fp32

    __bf16* wpack = (__bf16*)d_ws;               // 64 frags * 64 * 8 = 64 KB
    __bf16* y     = wpack + 32768;               // (256,32,128) bf16 = 2 MB

    pack_w_kernel<<<64, 64, 0, stream>>>(W, wpack);
    tree128_kernel<<<4096, 256, 0, stream>>>(wid, emb, wpack, b, y);
    tree32_kernel<<<256, 256, 0, stream>>>(y, wpack, b, out);
}

// Round 6
// 145.483 us; speedup vs baseline: 2.6553x; 2.6553x over previous
//
#include <hip/hip_runtime.h>

// RecursiveNN: 11-level binary tree, shared linear map W(128x256)+b, bf16 MFMA.
// pack_w: W -> per-lane MFMA B-fragment order (bf16), indexed by (N-tile, kk).
// tree128: one block = 128 contiguous leaves; fp32 gather + packed cvt -> LDS.
//   XOR-swizzled LDS (stride 128, 16B-chunk ^ row&15) -> exactly 40 KiB.
//   2x2 wave split: mw = M-half, nw = 64-col N-half. Each wave holds 32 W
//   fragments (128 VGPR) -> halves LDS A-read redundancy vs 4-way N-split.
//   NOTE: __launch_bounds__(256,2) NOT (256,3): the 170-VGPR cap of min-waves=3
//   forces wf[] to spill to scratch (R5: 587 MB scratch writes, 386 us).
// tree32: one block = one batch; final 5 levels (32->1); fp32 output.

typedef __bf16 bf16x8 __attribute__((ext_vector_type(8)));
typedef __bf16 bf16x4 __attribute__((ext_vector_type(4)));
typedef float f32x4 __attribute__((ext_vector_type(4)));

// Swizzled LDS offset: row stride 128 elems (256 B); 16B chunk index XORed
// with (row & 15). Conflict-free (measured 0 in R5) and all row bases fold
// into ds-instruction immediates. All buffer bases must be 16-row aligned.
__device__ __forceinline__ int sw_off(int row, int col) {
    return row * 128 + ((((col >> 3) ^ (row & 15)) << 3) | (col & 7));
}

// Pack W (fp32 128x256) into MFMA B-fragment lane order (bf16):
//   global frag gf = nt*8 + kk (N-tile nt = cols nt*16..+16), lane l:
//   elem j = W[o][d+j], o = nt*16 + (l&15), d = kk*32 + (l>>4)*8.
__global__ void pack_w_kernel(const float* __restrict__ W,
                              __bf16* __restrict__ wpack) {
    const int gf = blockIdx.x;       // 0..63
    const int l = threadIdx.x;       // 0..63
    const int nt = gf >> 3, kk = gf & 7;
    const int o = nt * 16 + (l & 15);
    const int d = kk * 32 + ((l >> 4) << 3);
    const float* src = W + o * 256 + d;
    bf16x8 h;
#pragma unroll
    for (int j = 0; j < 8; ++j) h[j] = (__bf16)src[j];
    *(bf16x8*)(wpack + (size_t)(gf * 64 + l) * 8) = h;
}

// One 16-row M-tile: reads input rows 0..2*NOUT-1 (pairs 2m,2m+1) from src,
// computes this wave's 64 cols (4 N-tiles), writes NOUT rows to dst.
// Padded lanes clamp to row 0 (LDS same-address broadcast, free).
template <int NOUT>
__device__ __forceinline__ void step_tile(
    const __bf16* __restrict__ src, __bf16* __restrict__ dst,
    const bf16x8* wf, const float* bval, int nw, int q, int lm)
{
    const int me = (NOUT >= 16) ? lm : (lm < NOUT ? lm : 0);
    f32x4 acc[4];
#pragma unroll
    for (int nl = 0; nl < 4; ++nl)
        acc[nl] = (f32x4){ bval[nl], bval[nl], bval[nl], bval[nl] };
#pragma unroll
    for (int kk = 0; kk < 8; ++kk) {
        const int row = 2 * me + (kk >> 2);            // k>=128 half -> +1
        const int col = (kk & 3) * 32 + q * 8;
        const bf16x8 af = *(const bf16x8*)&src[sw_off(row, col)];
#pragma unroll
        for (int nl = 0; nl < 4; ++nl)
            acc[nl] = __builtin_amdgcn_mfma_f32_16x16x32_bf16(
                af, wf[nl * 8 + kk], acc[nl], 0, 0, 0);
    }
#pragma unroll
    for (int nl = 0; nl < 4; ++nl) {
        const int col = (nw * 4 + nl) * 16 + lm;       // D col = lane&15
        const bf16x4 hv = __builtin_convertvector(acc[nl], bf16x4);
#pragma unroll
        for (int r = 0; r < 4; ++r) {
            const int row = q * 4 + r;                 // D row = quad*4+reg
            if (NOUT >= 16 || row < NOUT)
                dst[sw_off(row, col)] = hv[r];
        }
    }
}

// Final step: 4 src rows -> 2 roots straight to global (bf16).
__device__ __forceinline__ void final_tile(
    const __bf16* __restrict__ src, __bf16* __restrict__ yrow,
    const bf16x8* wf, const float* bval, int nw, int q, int lm)
{
    const int me = (lm < 2) ? lm : 0;
    f32x4 acc[4];
#pragma unroll
    for (int nl = 0; nl < 4; ++nl)
        acc[nl] = (f32x4){ bval[nl], bval[nl], bval[nl], bval[nl] };
#pragma unroll
    for (int kk = 0; kk < 8; ++kk) {
        const int row = 2 * me + (kk >> 2);
        const int col = (kk & 3) * 32 + q * 8;
        const bf16x8 af = *(const bf16x8*)&src[sw_off(row, col)];
#pragma unroll
        for (int nl = 0; nl < 4; ++nl)
            acc[nl] = __builtin_amdgcn_mfma_f32_16x16x32_bf16(
                af, wf[nl * 8 + kk], acc[nl], 0, 0, 0);
    }
#pragma unroll
    for (int nl = 0; nl < 4; ++nl) {
        const int col = (nw * 4 + nl) * 16 + lm;
        if (q == 0) {                                  // rows 0,1 = q0 regs 0,1
            yrow[0 * 128 + col] = (__bf16)acc[nl][0];
            yrow[1 * 128 + col] = (__bf16)acc[nl][1];
        }
    }
}

// Kernel 1: one block = 128 contiguous leaves of one batch.
// Node order after s1/s2: S[0:15]=n0-15, S[16:31]=n16-31, A[0:15]=n32-47,
// A[16:31]=n48-63. Schedule (all bases 16-row aligned):
//   s1: mw0 A[0:31]->S[0:15],   mw1 A[32:63]->S[16:31]
//   s2: mw0 A[64:95]->A[0:15],  mw1 A[96:127]->A[16:31]
//   L2: mw0 S[0:31]->A[32:47],  mw1 A[0:31]->A[48:63]
//   L3: mw0 A[32:63]->S[0:15]
//   L4: mw0 S->A[0:7]   L5: mw0 A->S[0:3]   L6: mw0 S->global (2 rows)
__global__ __launch_bounds__(256, 2) void tree128_kernel(
    const int* __restrict__ wid, const float* __restrict__ emb,
    const __bf16* __restrict__ wpack, const float* __restrict__ bias,
    __bf16* __restrict__ yout)
{
    __shared__ __align__(16) __bf16 A[128 * 128];  // 32 KiB
    __shared__ __align__(16) __bf16 S[32 * 128];   // 8 KiB -> 40 KiB total
    const int tid = threadIdx.x;
    const int batch = blockIdx.x >> 4;   // 16 groups of 128 leaves per batch
    const int grp = blockIdx.x & 15;
    const int wv = tid >> 6, nw = wv & 1, mw = wv >> 1;
    const int ln = tid & 63, q = ln >> 4, lm = ln & 15;

    // Gather 128 rows x 128 fp32 -> bf16 swizzled LDS (512B coalesced runs).
    {
        const int* wb = wid + batch * 2048 + grp * 128;
        int idreg[16];
#pragma unroll
        for (int i = 0; i < 16; ++i) idreg[i] = wb[(tid >> 5) + 8 * i];
#pragma unroll
        for (int i = 0; i < 16; ++i) {
            const int row = (tid >> 5) + 8 * i;
            const int c4 = tid & 31;
            const f32x4 v =
                *(const f32x4*)(emb + (size_t)idreg[i] * 128 + c4 * 4);
            *(bf16x4*)&A[sw_off(row, c4 * 4)] =
                __builtin_convertvector(v, bf16x4);
        }
    }

    // W fragments for this wave's 64 cols: 32 x bf16x8 = 128 VGPRs.
    bf16x8 wf[32];
    const bf16x8* wp = (const bf16x8*)wpack;
#pragma unroll
    for (int f = 0; f < 32; ++f) wf[f] = wp[(nw * 32 + f) * 64 + ln];
    float bval[4];
#pragma unroll
    for (int nl = 0; nl < 4; ++nl) bval[nl] = bias[(nw * 4 + nl) * 16 + lm];

    __syncthreads();

    step_tile<16>(A + mw * 32 * 128, S + mw * 16 * 128, wf, bval, nw, q, lm);
    __syncthreads();
    step_tile<16>(A + (64 + mw * 32) * 128, A + mw * 16 * 128,
                  wf, bval, nw, q, lm);
    __syncthreads();
    step_tile<16>(mw ? A : S, A + (32 + mw * 16) * 128, wf, bval, nw, q, lm);
    __syncthreads();
    if (mw == 0) step_tile<16>(A + 32 * 128, S, wf, bval, nw, q, lm);
    __syncthreads();
    if (mw == 0) step_tile<8>(S, A, wf, bval, nw, q, lm);
    __syncthreads();
    if (mw == 0) step_tile<4>(A, S, wf, bval, nw, q, lm);
    __syncthreads();
    if (mw == 0)
        final_tile(S, yout + (size_t)(batch * 32 + grp * 2) * 128,
                   wf, bval, nw, q, lm);
}

// Kernel 2: one block = one batch; 32 subtree roots -> 5 levels -> fp32 row.
// (4-way N-split, padded-stride LDS; tiny kernel, layout doesn't matter.)
#define STRIDE 136
__global__ __launch_bounds__(256) void tree32_kernel(
    const __bf16* __restrict__ yin, const __bf16* __restrict__ wpack,
    const float* __restrict__ bias, float* __restrict__ out)
{
    __shared__ __align__(16) __bf16 buf[2][32 * STRIDE];  // ~17.4 KB
    const int tid = threadIdx.x;
    const int batch = blockIdx.x;
    const int wv = tid >> 6, ln = tid & 63, q = ln >> 4, lm = ln & 15;

    // wave wv owns N-tiles {2wv, 2wv+1}: frag f=nl*8+kk at gf = 16wv + f.
    bf16x8 wf[16];
    const bf16x8* wp = (const bf16x8*)wpack;
#pragma unroll
    for (int f = 0; f < 16; ++f) wf[f] = wp[(16 * wv + f) * 64 + ln];
    float bval[2];
    bval[0] = bias[(2 * wv + 0) * 16 + lm];
    bval[1] = bias[(2 * wv + 1) * 16 + lm];

#pragma unroll
    for (int i = 0; i < 2; ++i) {
        const int flat = tid + 256 * i;
        const int row = flat >> 4;
        const int c8 = flat & 15;
        const bf16x8 v =
            *(const bf16x8*)(yin + (size_t)(batch * 32 + row) * 128 + c8 * 8);
        *(bf16x8*)&buf[0][row * STRIDE + c8 * 8] = v;
    }
    __syncthreads();

    int nin = 32, rb = 0;
    while (nin > 1) {
        const int nout = nin >> 1;
        const int me = (lm < nout) ? lm : 0;
        bf16x8 af[8];
#pragma unroll
        for (int kk = 0; kk < 8; ++kk) {
            const int hi = kk >> 2;
            const int col = (kk & 3) * 32 + q * 8;
            af[kk] = *(const bf16x8*)&buf[rb][(2 * me + hi) * STRIDE + col];
        }
#pragma unroll
        for (int nl = 0; nl < 2; ++nl) {
            f32x4 acc = { bval[nl], bval[nl], bval[nl], bval[nl] };
#pragma unroll
            for (int kk = 0; kk < 8; ++kk)
                acc = __builtin_amdgcn_mfma_f32_16x16x32_bf16(
                    af[kk], wf[nl * 8 + kk], acc, 0, 0, 0);
            const int col = (2 * wv + nl) * 16 + lm;
            if (nout == 1) {
                if (q == 0) out[(size_t)batch * 128 + col] = acc[0];
            } else {
                const bf16x4 hv = __builtin_convertvector(acc, bf16x4);
#pragma unroll
                for (int r = 0; r < 4; ++r) {
                    const int row = q * 4 + r;
                    if (row < nout)
                        buf[rb ^ 1][row * STRIDE + col] = hv[r];
                }
            }
        }
        __syncthreads();
        rb ^= 1;
        nin = nout;
    }
}

extern "C" void kernel_launch(void* const* d_in, const int* in_sizes, int n_in,
                              void* d_out, int out_size, void* d_ws, size_t ws_size,
                              hipStream_t stream) {
    const int*   wid = (const int*)d_in[0];      // (256, 2048) int32
    const float* emb = (const float*)d_in[1];    // (100000, 128) fp32
    const float* W   = (const float*)d_in[2];    // (128, 256) fp32
    const float* b   = (const float*)d_in[3];    // (128,) fp32
    float* out = (float*)d_out;                  // (256, 128) fp32

    __bf16* wpack = (__bf16*)d_ws;               // 64 frags * 64 * 8 = 64 KB
    __bf16* y     = wpack + 32768;               // (256,32,128) bf16 = 2 MB

    pack_w_kernel<<<64, 64, 0, stream>>>(W, wpack);
    tree128_kernel<<<4096, 256, 0, stream>>>(wid, emb, wpack, b, y);
    tree32_kernel<<<256, 256, 0, stream>>>(y, wpack, b, out);
}